// Round 12
// baseline (595.410 us; speedup 1.0000x reference)
//
#include <hip/hip_runtime.h>
#include <hip/hip_fp16.h>
#include <cstddef>
#include <cstdint>

#define N_NODES   100000
#define N_EDGES   1600000
#define N_GRAPHS  512
#define HIDDEN    128
#define N_LAYERS  3

// 400-way counting sort (R9-confirmed)
#define N_WIN      400
#define WIN_NODES  (N_NODES / N_WIN)        // 250
#define BIN_BLOCKS 512
#define BIN_CHUNK  (N_EDGES / BIN_BLOCKS)   // 3125 exactly

typedef _Float16 half8 __attribute__((ext_vector_type(8)));
typedef float    float8 __attribute__((ext_vector_type(8)));
typedef float    floatx4 __attribute__((ext_vector_type(4)));
typedef float    floatx2 __attribute__((ext_vector_type(2)));

// ---------------------------------------------------------------------------
__global__ __launch_bounds__(256) void win_count_kernel(const int* __restrict__ dst,
                                                        int* __restrict__ counts) {
    __shared__ int cs[N_WIN];
    for (int i = threadIdx.x; i < N_WIN; i += 256) cs[i] = 0;
    __syncthreads();
    const int e0 = blockIdx.x * BIN_CHUNK, e1 = e0 + BIN_CHUNK;
    for (int e = e0 + threadIdx.x; e < e1; e += 256)
        atomicAdd(&cs[dst[e] / WIN_NODES], 1);
    __syncthreads();
    for (int i = threadIdx.x; i < N_WIN; i += 256)
        counts[blockIdx.x * N_WIN + i] = cs[i];
}

__global__ __launch_bounds__(512) void win_scan1_kernel(const int* __restrict__ counts,
                                                        int* __restrict__ offsets,
                                                        int* __restrict__ colsum) {
    __shared__ int tmp[512];
    const int w = blockIdx.x;
    const int t = threadIdx.x;
    tmp[t] = counts[t * N_WIN + w];
    __syncthreads();
#pragma unroll
    for (int off = 1; off < 512; off <<= 1) {
        int u = (t >= off) ? tmp[t - off] : 0;
        __syncthreads();
        tmp[t] += u;
        __syncthreads();
    }
    offsets[t * N_WIN + w] = (t == 0) ? 0 : tmp[t - 1];
    if (t == 511) colsum[w] = tmp[511];
}

__global__ __launch_bounds__(512) void win_scan2_kernel(const int* __restrict__ colsum,
                                                        int* __restrict__ winbase) {
    __shared__ int tmp[512];
    const int t = threadIdx.x;
    tmp[t] = (t < N_WIN) ? colsum[t] : 0;
    __syncthreads();
#pragma unroll
    for (int off = 1; off < 512; off <<= 1) {
        int u = (t >= off) ? tmp[t - off] : 0;
        __syncthreads();
        tmp[t] += u;
        __syncthreads();
    }
    if (t < N_WIN) winbase[t] = (t == 0) ? 0 : tmp[t - 1];
    if (t == N_WIN - 1) winbase[N_WIN] = tmp[t];
}

__global__ __launch_bounds__(256) void win_place_kernel(const int* __restrict__ src,
                                                        const int* __restrict__ dst,
                                                        const int* __restrict__ offsets,
                                                        const int* __restrict__ winbase,
                                                        int2* __restrict__ wedge) {
    __shared__ int off[N_WIN];
    for (int i = threadIdx.x; i < N_WIN; i += 256)
        off[i] = offsets[blockIdx.x * N_WIN + i] + winbase[i];
    __syncthreads();
    const int e0 = blockIdx.x * BIN_CHUNK, e1 = e0 + BIN_CHUNK;
    for (int e = e0 + threadIdx.x; e < e1; e += 256) {
        int d = dst[e];
        int p = atomicAdd(&off[d / WIN_NODES], 1);
        wedge[p] = make_int2(d, src[e]);
    }
}

__global__ __launch_bounds__(256) void win_csr_kernel(const int2* __restrict__ wedge,
                                                      const int* __restrict__ winbase,
                                                      int* __restrict__ row_ptr,
                                                      int* __restrict__ csr_src) {
    __shared__ int cnt[WIN_NODES];
    __shared__ int tmp[256];
    const int w = blockIdx.x, n0 = w * WIN_NODES, t = threadIdx.x;
    for (int i = t; i < WIN_NODES; i += 256) cnt[i] = 0;
    __syncthreads();
    const int b0 = winbase[w], b1 = winbase[w + 1];
    for (int e = b0 + t; e < b1; e += 256)
        atomicAdd(&cnt[wedge[e].x - n0], 1);
    __syncthreads();
    tmp[t] = (t < WIN_NODES) ? cnt[t] : 0;
    __syncthreads();
#pragma unroll
    for (int off = 1; off < 256; off <<= 1) {
        int u = (t >= off) ? tmp[t - off] : 0;
        __syncthreads();
        tmp[t] += u;
        __syncthreads();
    }
    const int excl = (t == 0) ? 0 : tmp[t - 1];
    if (t < WIN_NODES) {
        row_ptr[n0 + t] = b0 + excl;
        cnt[t] = b0 + excl;
    }
    if (w == N_WIN - 1 && t == 0) row_ptr[N_NODES] = winbase[N_WIN];
    __syncthreads();
    for (int e = b0 + t; e < b1; e += 256) {
        int2 ed = wedge[e];
        int p = atomicAdd(&cnt[ed.x - n0], 1);
        csr_src[p] = ed.y;
    }
}

// ---------------------------------------------------------------------------
// X fp32 -> fp16 copy + fp8 (OCP e4m3) copy, one pass
// ---------------------------------------------------------------------------
__global__ void f2h_kernel(const float* __restrict__ in, __half* __restrict__ out,
                           unsigned char* __restrict__ outq) {
    int t = blockIdx.x * blockDim.x + threadIdx.x;
    const int n8 = (N_NODES * HIDDEN) / 8;
    if (t >= n8) return;
    const float4* in4 = (const float4*)in;
    float4 a = in4[t * 2 + 0];
    float4 b = in4[t * 2 + 1];
    __half2* o2 = (__half2*)out;
    o2[t * 4 + 0] = __floats2half2_rn(a.x, a.y);
    o2[t * 4 + 1] = __floats2half2_rn(a.z, a.w);
    o2[t * 4 + 2] = __floats2half2_rn(b.x, b.y);
    o2[t * 4 + 3] = __floats2half2_rn(b.z, b.w);
    unsigned r0 = 0, r1 = 0;
    r0 = __builtin_amdgcn_cvt_pk_fp8_f32(a.x, a.y, r0, false);
    r0 = __builtin_amdgcn_cvt_pk_fp8_f32(a.z, a.w, r0, true);
    r1 = __builtin_amdgcn_cvt_pk_fp8_f32(b.x, b.y, r1, false);
    r1 = __builtin_amdgcn_cvt_pk_fp8_f32(b.z, b.w, r1, true);
    ((uint2*)outq)[t] = make_uint2(r0, r1);
}

// fp16 -> fp8 copy (for layer outputs feeding the next gather)
__global__ void h2q_kernel(const __half* __restrict__ in, unsigned char* __restrict__ outq) {
    int t = blockIdx.x * blockDim.x + threadIdx.x;
    const int n8 = (N_NODES * HIDDEN) / 8;
    if (t >= n8) return;
    half8 v = ((const half8*)in)[t];
    float8 f = __builtin_convertvector(v, float8);
    unsigned r0 = 0, r1 = 0;
    r0 = __builtin_amdgcn_cvt_pk_fp8_f32(f[0], f[1], r0, false);
    r0 = __builtin_amdgcn_cvt_pk_fp8_f32(f[2], f[3], r0, true);
    r1 = __builtin_amdgcn_cvt_pk_fp8_f32(f[4], f[5], r1, false);
    r1 = __builtin_amdgcn_cvt_pk_fp8_f32(f[6], f[7], r1, true);
    ((uint2*)outq)[t] = make_uint2(r0, r1);
}

__global__ void wconv_kernel(const float* __restrict__ w1, const float* __restrict__ w2,
                             __half* __restrict__ wt1, __half* __restrict__ wt2) {
    int t = blockIdx.x * blockDim.x + threadIdx.x;
    if (t >= N_LAYERS * HIDDEN * HIDDEN) return;
    int l = t / (HIDDEN * HIDDEN);
    int r = t - l * (HIDDEN * HIDDEN);
    int k = r / HIDDEN, n = r - k * HIDDEN;
    wt1[(size_t)l * HIDDEN * HIDDEN + n * HIDDEN + k] = __float2half(w1[t]);
    wt2[(size_t)l * HIDDEN * HIDDEN + n * HIDDEN + k] = __float2half(w2[t]);
}

// ---------------------------------------------------------------------------
// GIN aggregation, fp8 neighbors: row = 128B = 8 lanes x 16B -> 8 neighbors
// per wave-load. grp=lane>>3 owns neighbor k+grp; m=lane&7 owns feats
// 16m..16m+15 (16 fp8). HW cvt_pk_f32_fp8 unpack; fp32 accumulate;
// butterfly xor 8/16/32; self term read exact from fp16; output fp16.
// (R11: fp16 gather at random-path floor 3.5TB/s -> only fewer bytes help.)
// ---------------------------------------------------------------------------
__device__ __forceinline__ void acc_fp8x16(float* acc, uint4 v) {
    floatx2 f;
    f = __builtin_amdgcn_cvt_pk_f32_fp8(v.x, false); acc[0] += f.x;  acc[1] += f.y;
    f = __builtin_amdgcn_cvt_pk_f32_fp8(v.x, true);  acc[2] += f.x;  acc[3] += f.y;
    f = __builtin_amdgcn_cvt_pk_f32_fp8(v.y, false); acc[4] += f.x;  acc[5] += f.y;
    f = __builtin_amdgcn_cvt_pk_f32_fp8(v.y, true);  acc[6] += f.x;  acc[7] += f.y;
    f = __builtin_amdgcn_cvt_pk_f32_fp8(v.z, false); acc[8] += f.x;  acc[9] += f.y;
    f = __builtin_amdgcn_cvt_pk_f32_fp8(v.z, true);  acc[10] += f.x; acc[11] += f.y;
    f = __builtin_amdgcn_cvt_pk_f32_fp8(v.w, false); acc[12] += f.x; acc[13] += f.y;
    f = __builtin_amdgcn_cvt_pk_f32_fp8(v.w, true);  acc[14] += f.x; acc[15] += f.y;
}

__global__ void gather_kernel(const unsigned char* __restrict__ Xq,
                              const __half* __restrict__ Xh,
                              __half* __restrict__ Zh,
                              const int* __restrict__ row_ptr,
                              const int* __restrict__ csr_src) {
    int wave = (blockIdx.x * blockDim.x + threadIdx.x) >> 6;
    int lane = threadIdx.x & 63;
    if (wave >= N_NODES) return;
    const int grp = lane >> 3;     // 0..7
    const int m   = lane & 7;      // 0..7
    const uint4* Q = (const uint4*)Xq;   // row = 8 x uint4 (128B)

    float acc[16];
#pragma unroll
    for (int j = 0; j < 16; ++j) acc[j] = 0.f;

    int k = row_ptr[wave];
    const int end = row_ptr[wave + 1];

    for (; k + 16 <= end; k += 16) {
        int n0 = csr_src[k + grp];
        int n1 = csr_src[k + 8 + grp];
        uint4 v0 = Q[(size_t)n0 * 8 + m];
        uint4 v1 = Q[(size_t)n1 * 8 + m];
        acc_fp8x16(acc, v0);
        acc_fp8x16(acc, v1);
    }
    if (k + 8 <= end) {
        int n0 = csr_src[k + grp];
        uint4 v0 = Q[(size_t)n0 * 8 + m];
        acc_fp8x16(acc, v0);
        k += 8;
    }
    int rem = end - k;             // 0..7
    if (grp < rem) {
        int n0 = csr_src[k + grp];
        uint4 v0 = Q[(size_t)n0 * 8 + m];
        acc_fp8x16(acc, v0);
    }

    // butterfly across the 8 groups (lanes ^8, ^16, ^32)
#pragma unroll
    for (int j = 0; j < 16; ++j) acc[j] += __shfl_xor(acc[j], 8);
#pragma unroll
    for (int j = 0; j < 16; ++j) acc[j] += __shfl_xor(acc[j], 16);
#pragma unroll
    for (int j = 0; j < 16; ++j) acc[j] += __shfl_xor(acc[j], 32);

    // self term, exact fp16 (feats 16m..16m+15 = half8 chunks 2m, 2m+1)
    const half8* H = (const half8*)Xh;   // row = 16 x half8
    half8 s0 = H[(size_t)wave * 16 + 2 * m];
    half8 s1 = H[(size_t)wave * 16 + 2 * m + 1];
    float8 sf0 = __builtin_convertvector(s0, float8);
    float8 sf1 = __builtin_convertvector(s1, float8);
#pragma unroll
    for (int j = 0; j < 8; ++j) { acc[j] += sf0[j]; acc[8 + j] += sf1[j]; }

    if (grp == 0) {
        half8 o0, o1;
#pragma unroll
        for (int j = 0; j < 8; ++j) { o0[j] = (_Float16)acc[j]; o1[j] = (_Float16)acc[8 + j]; }
        ((half8*)Zh)[(size_t)wave * 16 + 2 * m]     = o0;
        ((half8*)Zh)[(size_t)wave * 16 + 2 * m + 1] = o1;
    }
}

// ---------------------------------------------------------------------------
// Register-resident-W MFMA stage (R11-confirmed): C = relu(A@W + bias).
// ---------------------------------------------------------------------------
#define MM_BLOCKS 512
__global__ __launch_bounds__(256, 2) void mm_stage_kernel(const __half* __restrict__ A,
                                                          const __half* __restrict__ Wt,
                                                          const float* __restrict__ bias,
                                                          __half* __restrict__ C16) {
    const int gwave = (blockIdx.x * 256 + threadIdx.x) >> 6;
    const int lane  = threadIdx.x & 63;
    const int m = lane & 15;
    const int q = lane >> 4;
    const int nwaves = MM_BLOCKS * 4;
    const int NTILES = N_NODES / 16;   // 6250

    half8 wf[8][4];
    float bl[8];
#pragma unroll
    for (int ct = 0; ct < 8; ++ct) {
        const half8* Wrow = (const half8*)(Wt + (size_t)(ct * 16 + m) * HIDDEN);
#pragma unroll
        for (int c = 0; c < 4; ++c) wf[ct][c] = Wrow[c * 4 + q];
        bl[ct] = bias[ct * 16 + m];
    }

    for (int t = gwave; t < NTILES; t += nwaves) {
        const half8* Arow = (const half8*)(A + (size_t)(t * 16 + m) * HIDDEN);
        half8 a0 = Arow[q];
        half8 a1 = Arow[4 + q];
        half8 a2 = Arow[8 + q];
        half8 a3 = Arow[12 + q];
#pragma unroll
        for (int ct = 0; ct < 8; ++ct) {
            floatx4 acc = {0.f, 0.f, 0.f, 0.f};
            acc = __builtin_amdgcn_mfma_f32_16x16x32_f16(a0, wf[ct][0], acc, 0, 0, 0);
            acc = __builtin_amdgcn_mfma_f32_16x16x32_f16(a1, wf[ct][1], acc, 0, 0, 0);
            acc = __builtin_amdgcn_mfma_f32_16x16x32_f16(a2, wf[ct][2], acc, 0, 0, 0);
            acc = __builtin_amdgcn_mfma_f32_16x16x32_f16(a3, wf[ct][3], acc, 0, 0, 0);
            const int n = ct * 16 + m;
#pragma unroll
            for (int r = 0; r < 4; ++r) {
                int row = t * 16 + q * 4 + r;
                float v = fmaxf(acc[r] + bl[ct], 0.f);
                C16[(size_t)row * HIDDEN + n] = __float2half(v);
            }
        }
    }
}

// ---------------------------------------------------------------------------
#define POOL_CHUNK 128
__global__ void pool_kernel(const __half* __restrict__ Xh, const int* __restrict__ batch,
                            float* __restrict__ pooled, int layer) {
    const int f = threadIdx.x;
    int start = blockIdx.x * POOL_CHUNK;
    int end = start + POOL_CHUNK;
    if (end > N_NODES) end = N_NODES;
    float acc = 0.f;
    int gcur = batch[start];
    for (int n = start; n < end; ++n) {
        int g = batch[n];
        if (g != gcur) {
            atomicAdd(&pooled[(size_t)gcur * (HIDDEN * N_LAYERS) + layer * HIDDEN + f], acc);
            acc = 0.f;
            gcur = g;
        }
        acc += __half2float(Xh[(size_t)n * HIDDEN + f]);
    }
    atomicAdd(&pooled[(size_t)gcur * (HIDDEN * N_LAYERS) + layer * HIDDEN + f], acc);
}

// ---------------------------------------------------------------------------
__global__ __launch_bounds__(128) void cls_kernel(const float* __restrict__ pooled,
                                                  const float* __restrict__ w1,
                                                  const float* __restrict__ b1,
                                                  const float* __restrict__ w2,
                                                  const float* __restrict__ b2,
                                                  const float* __restrict__ w3,
                                                  const float* __restrict__ b3,
                                                  float* __restrict__ out) {
    __shared__ float hin[HIDDEN * N_LAYERS];
    __shared__ float h1[HIDDEN];
    __shared__ float red[HIDDEN];
    const int g = blockIdx.x;
    const int t = threadIdx.x;

    for (int i = t; i < HIDDEN * N_LAYERS; i += 128)
        hin[i] = pooled[(size_t)g * (HIDDEN * N_LAYERS) + i];
    __syncthreads();

    float s = 0.f;
    for (int k = 0; k < HIDDEN * N_LAYERS; ++k) s += hin[k] * w1[(size_t)k * HIDDEN + t];
    s = fmaxf(s + b1[t], 0.f);
    h1[t] = s;
    __syncthreads();

    float s2 = 0.f;
    for (int k = 0; k < HIDDEN; ++k) s2 += h1[k] * w2[(size_t)k * HIDDEN + t];
    s2 = fmaxf(s2 + b2[t], 0.f);

    red[t] = s2 * w3[t];
    __syncthreads();
    for (int off = 64; off > 0; off >>= 1) {
        if (t < off) red[t] += red[t + off];
        __syncthreads();
    }
    if (t == 0) out[g] = red[0] + b3[0];
}

// ---------------------------------------------------------------------------
extern "C" void kernel_launch(void* const* d_in, const int* in_sizes, int n_in,
                              void* d_out, int out_size, void* d_ws, size_t ws_size,
                              hipStream_t stream) {
    const float* X     = (const float*)d_in[0];
    const int*   ei    = (const int*)d_in[1];
    const int*   batch = (const int*)d_in[2];
    const float* w1all = (const float*)d_in[3];
    const float* b1all = (const float*)d_in[4];
    const float* w2all = (const float*)d_in[5];
    const float* b2all = (const float*)d_in[6];
    const float* cw1   = (const float*)d_in[7];
    const float* cb1   = (const float*)d_in[8];
    const float* cw2   = (const float*)d_in[9];
    const float* cb2   = (const float*)d_in[10];
    const float* cw3   = (const float*)d_in[11];
    const float* cb3   = (const float*)d_in[12];
    float* out = (float*)d_out;

    const int* src = ei;
    const int* dst = ei + N_EDGES;

    char* p = (char*)d_ws;
    auto alloc = (size_t (*)(void))nullptr; (void)alloc;
    auto alloc2 = [&](size_t bytes) {
        char* r = p;
        p += (bytes + 255) & ~(size_t)255;
        return r;
    };
    __half* hA      = (__half*)alloc2((size_t)N_NODES * HIDDEN * sizeof(__half));
    __half* hB      = (__half*)alloc2((size_t)N_NODES * HIDDEN * sizeof(__half));
    __half* zh      = (__half*)alloc2((size_t)N_NODES * HIDDEN * sizeof(__half));
    __half* m1h     = (__half*)alloc2((size_t)N_NODES * HIDDEN * sizeof(__half));
    unsigned char* qbuf = (unsigned char*)alloc2((size_t)N_NODES * HIDDEN);
    __half* wt1     = (__half*)alloc2((size_t)N_LAYERS * HIDDEN * HIDDEN * sizeof(__half));
    __half* wt2     = (__half*)alloc2((size_t)N_LAYERS * HIDDEN * HIDDEN * sizeof(__half));
    int2*   wedge   = (int2*)alloc2((size_t)N_EDGES * sizeof(int2));
    int*    csr     = (int*)alloc2((size_t)N_EDGES * sizeof(int));
    int*    rowp    = (int*)alloc2((size_t)(N_NODES + 1) * sizeof(int));
    int*    counts  = (int*)alloc2((size_t)BIN_BLOCKS * N_WIN * sizeof(int));
    int*    offsets = (int*)alloc2((size_t)BIN_BLOCKS * N_WIN * sizeof(int));
    int*    colsum  = (int*)alloc2((size_t)N_WIN * sizeof(int));
    int*    winbase = (int*)alloc2((size_t)(N_WIN + 1) * sizeof(int));
    float*  pooled  = (float*)alloc2((size_t)N_GRAPHS * HIDDEN * N_LAYERS * sizeof(float));

    hipMemsetAsync(pooled, 0, (size_t)N_GRAPHS * HIDDEN * N_LAYERS * sizeof(float), stream);

    win_count_kernel<<<BIN_BLOCKS, 256, 0, stream>>>(dst, counts);
    win_scan1_kernel<<<N_WIN, 512, 0, stream>>>(counts, offsets, colsum);
    win_scan2_kernel<<<1, 512, 0, stream>>>(colsum, winbase);
    win_place_kernel<<<BIN_BLOCKS, 256, 0, stream>>>(src, dst, offsets, winbase, wedge);
    win_csr_kernel<<<N_WIN, 256, 0, stream>>>(wedge, winbase, rowp, csr);

    const int cvt_grid = ((N_NODES * HIDDEN / 8) + 255) / 256;
    f2h_kernel<<<cvt_grid, 256, 0, stream>>>(X, hA, qbuf);
    wconv_kernel<<<(N_LAYERS * HIDDEN * HIDDEN + 255) / 256, 256, 0, stream>>>(w1all, w2all, wt1, wt2);

    const int gat_grid  = (N_NODES + 3) / 4;
    const int pool_grid = (N_NODES + POOL_CHUNK - 1) / POOL_CHUNK;

    __half* hcur = hA;
    for (int l = 0; l < N_LAYERS; ++l) {
        __half* hnext = (l & 1) ? hA : hB;
        gather_kernel<<<gat_grid, 256, 0, stream>>>(qbuf, hcur, zh, rowp, csr);
        mm_stage_kernel<<<MM_BLOCKS, 256, 0, stream>>>(zh,
                                                       wt1 + (size_t)l * HIDDEN * HIDDEN,
                                                       b1all + (size_t)l * HIDDEN,
                                                       m1h);
        mm_stage_kernel<<<MM_BLOCKS, 256, 0, stream>>>(m1h,
                                                       wt2 + (size_t)l * HIDDEN * HIDDEN,
                                                       b2all + (size_t)l * HIDDEN,
                                                       hnext);
        pool_kernel<<<pool_grid, POOL_CHUNK, 0, stream>>>(hnext, batch, pooled, l);
        if (l < N_LAYERS - 1)
            h2q_kernel<<<cvt_grid, 256, 0, stream>>>(hnext, qbuf);
        hcur = hnext;
    }

    cls_kernel<<<N_GRAPHS, 128, 0, stream>>>(pooled, cw1, cb1, cw2, cb2, cw3, cb3, out);
}

// Round 13
// 487.455 us; speedup vs baseline: 1.2215x; 1.2215x over previous
//
#include <hip/hip_runtime.h>
#include <hip/hip_fp16.h>
#include <cstddef>
#include <cstdint>

#define N_NODES   100000
#define N_EDGES   1600000
#define N_GRAPHS  512
#define HIDDEN    128
#define N_LAYERS  3

// 400-way counting sort (R9-confirmed). Place/count blocks = 128 so each
// block's per-window run is ~31 edges (~250B) -> near-full-line wedge writes
// (R7/R8 lesson: sub-line scattered writes from many blocks = 8x write amp).
#define N_WIN        400
#define WIN_NODES    (N_NODES / N_WIN)      // 250
#define PLACE_BLOCKS 128
#define PCHUNK       (N_EDGES / PLACE_BLOCKS)  // 12500, divisible by 4

typedef _Float16 half8  __attribute__((ext_vector_type(8)));
typedef _Float16 half2v __attribute__((ext_vector_type(2)));
typedef float    float8 __attribute__((ext_vector_type(8)));
typedef float    floatx4 __attribute__((ext_vector_type(4)));
typedef float    floatx2 __attribute__((ext_vector_type(2)));

// ---------------------------------------------------------------------------
__global__ __launch_bounds__(256) void win_count_kernel(const int* __restrict__ dst,
                                                        int* __restrict__ counts) {
    __shared__ int cs[N_WIN];
    for (int i = threadIdx.x; i < N_WIN; i += 256) cs[i] = 0;
    __syncthreads();
    const int4* d4 = (const int4*)(dst + blockIdx.x * PCHUNK);
    for (int i = threadIdx.x; i < PCHUNK / 4; i += 256) {
        int4 d = d4[i];
        atomicAdd(&cs[d.x / WIN_NODES], 1);
        atomicAdd(&cs[d.y / WIN_NODES], 1);
        atomicAdd(&cs[d.z / WIN_NODES], 1);
        atomicAdd(&cs[d.w / WIN_NODES], 1);
    }
    __syncthreads();
    for (int i = threadIdx.x; i < N_WIN; i += 256)
        counts[blockIdx.x * N_WIN + i] = cs[i];
}

// column scan over the 128 place-blocks
__global__ __launch_bounds__(128) void win_scan1_kernel(const int* __restrict__ counts,
                                                        int* __restrict__ offsets,
                                                        int* __restrict__ colsum) {
    __shared__ int tmp[128];
    const int w = blockIdx.x;
    const int t = threadIdx.x;
    tmp[t] = counts[t * N_WIN + w];
    __syncthreads();
#pragma unroll
    for (int off = 1; off < 128; off <<= 1) {
        int u = (t >= off) ? tmp[t - off] : 0;
        __syncthreads();
        tmp[t] += u;
        __syncthreads();
    }
    offsets[t * N_WIN + w] = (t == 0) ? 0 : tmp[t - 1];
    if (t == 127) colsum[w] = tmp[127];
}

__global__ __launch_bounds__(512) void win_scan2_kernel(const int* __restrict__ colsum,
                                                        int* __restrict__ winbase) {
    __shared__ int tmp[512];
    const int t = threadIdx.x;
    tmp[t] = (t < N_WIN) ? colsum[t] : 0;
    __syncthreads();
#pragma unroll
    for (int off = 1; off < 512; off <<= 1) {
        int u = (t >= off) ? tmp[t - off] : 0;
        __syncthreads();
        tmp[t] += u;
        __syncthreads();
    }
    if (t < N_WIN) winbase[t] = (t == 0) ? 0 : tmp[t - 1];
    if (t == N_WIN - 1) winbase[N_WIN] = tmp[t];
}

__global__ __launch_bounds__(256) void win_place_kernel(const int* __restrict__ src,
                                                        const int* __restrict__ dst,
                                                        const int* __restrict__ offsets,
                                                        const int* __restrict__ winbase,
                                                        int2* __restrict__ wedge) {
    __shared__ int off[N_WIN];
    for (int i = threadIdx.x; i < N_WIN; i += 256)
        off[i] = offsets[blockIdx.x * N_WIN + i] + winbase[i];
    __syncthreads();
    const int4* d4 = (const int4*)(dst + blockIdx.x * PCHUNK);
    const int4* s4 = (const int4*)(src + blockIdx.x * PCHUNK);
    for (int i = threadIdx.x; i < PCHUNK / 4; i += 256) {
        int4 d = d4[i];
        int4 s = s4[i];
        int p0 = atomicAdd(&off[d.x / WIN_NODES], 1); wedge[p0] = make_int2(d.x, s.x);
        int p1 = atomicAdd(&off[d.y / WIN_NODES], 1); wedge[p1] = make_int2(d.y, s.y);
        int p2 = atomicAdd(&off[d.z / WIN_NODES], 1); wedge[p2] = make_int2(d.z, s.z);
        int p3 = atomicAdd(&off[d.w / WIN_NODES], 1); wedge[p3] = make_int2(d.w, s.w);
    }
}

// fused per-window CSR: count (LDS) -> in-block scan -> row_ptr -> scatter
__global__ __launch_bounds__(256) void win_csr_kernel(const int2* __restrict__ wedge,
                                                      const int* __restrict__ winbase,
                                                      int* __restrict__ row_ptr,
                                                      int* __restrict__ csr_src) {
    __shared__ int cnt[WIN_NODES];
    __shared__ int tmp[256];
    const int w = blockIdx.x, n0 = w * WIN_NODES, t = threadIdx.x;
    for (int i = t; i < WIN_NODES; i += 256) cnt[i] = 0;
    __syncthreads();
    const int b0 = winbase[w], b1 = winbase[w + 1];
    for (int e = b0 + t; e < b1; e += 256)
        atomicAdd(&cnt[wedge[e].x - n0], 1);
    __syncthreads();
    tmp[t] = (t < WIN_NODES) ? cnt[t] : 0;
    __syncthreads();
#pragma unroll
    for (int off = 1; off < 256; off <<= 1) {
        int u = (t >= off) ? tmp[t - off] : 0;
        __syncthreads();
        tmp[t] += u;
        __syncthreads();
    }
    const int excl = (t == 0) ? 0 : tmp[t - 1];
    if (t < WIN_NODES) {
        row_ptr[n0 + t] = b0 + excl;
        cnt[t] = b0 + excl;
    }
    if (w == N_WIN - 1 && t == 0) row_ptr[N_NODES] = winbase[N_WIN];
    __syncthreads();
    for (int e = b0 + t; e < b1; e += 256) {
        int2 ed = wedge[e];
        int p = atomicAdd(&cnt[ed.x - n0], 1);
        csr_src[p] = ed.y;
    }
}

// ---------------------------------------------------------------------------
// X fp32 -> fp16 copy + fp8 (OCP e4m3) copy, one pass
// ---------------------------------------------------------------------------
__global__ void f2h_kernel(const float* __restrict__ in, __half* __restrict__ out,
                           unsigned char* __restrict__ outq) {
    int t = blockIdx.x * blockDim.x + threadIdx.x;
    const int n8 = (N_NODES * HIDDEN) / 8;
    if (t >= n8) return;
    const float4* in4 = (const float4*)in;
    float4 a = in4[t * 2 + 0];
    float4 b = in4[t * 2 + 1];
    __half2* o2 = (__half2*)out;
    o2[t * 4 + 0] = __floats2half2_rn(a.x, a.y);
    o2[t * 4 + 1] = __floats2half2_rn(a.z, a.w);
    o2[t * 4 + 2] = __floats2half2_rn(b.x, b.y);
    o2[t * 4 + 3] = __floats2half2_rn(b.z, b.w);
    unsigned r0 = 0, r1 = 0;
    r0 = __builtin_amdgcn_cvt_pk_fp8_f32(a.x, a.y, r0, false);
    r0 = __builtin_amdgcn_cvt_pk_fp8_f32(a.z, a.w, r0, true);
    r1 = __builtin_amdgcn_cvt_pk_fp8_f32(b.x, b.y, r1, false);
    r1 = __builtin_amdgcn_cvt_pk_fp8_f32(b.z, b.w, r1, true);
    ((uint2*)outq)[t] = make_uint2(r0, r1);
}

// ---------------------------------------------------------------------------
// Weight transpose via LDS tiles (old scalar version: 64 lanes x 2B stores to
// 64 distinct lines = ~30x write amp). grid = 3 layers x 2 mats x 16 tiles.
// ---------------------------------------------------------------------------
__global__ __launch_bounds__(256) void wconv_kernel(const float* __restrict__ w1,
                                                    const float* __restrict__ w2,
                                                    __half* __restrict__ wt1,
                                                    __half* __restrict__ wt2) {
    __shared__ float tile[32][33];
    const int b = blockIdx.x;
    const int mat = b & 1;
    const int tt = (b >> 1) & 15;
    const int l  = b >> 5;
    const int ti = (tt >> 2) * 32, tj = (tt & 3) * 32;
    const float* W = (mat ? w2 : w1) + (size_t)l * HIDDEN * HIDDEN;
    __half* WT = (mat ? wt2 : wt1) + (size_t)l * HIDDEN * HIDDEN;
    const int r = threadIdx.x >> 5;    // 0..7
    const int c = threadIdx.x & 31;    // 0..31
#pragma unroll
    for (int rr = 0; rr < 4; ++rr)
        tile[r + 8 * rr][c] = W[(size_t)(ti + r + 8 * rr) * HIDDEN + tj + c];
    __syncthreads();
#pragma unroll
    for (int rr = 0; rr < 4; ++rr)
        WT[(size_t)(tj + r + 8 * rr) * HIDDEN + ti + c] =
            __float2half(tile[c][r + 8 * rr]);
}

// ---------------------------------------------------------------------------
// GIN aggregation, fp8 neighbors (R12): 8 rows per wave-load, fp32 row accum.
// NEW: cross-lane reduction in packed fp16 (8 half2, v_pk_add_f16) -- halves
// the butterfly op count (R12: VALU-bound at 47% VALUBusy, not byte-bound).
// ---------------------------------------------------------------------------
__device__ __forceinline__ void acc_fp8x16(float* acc, uint4 v) {
    floatx2 f;
    f = __builtin_amdgcn_cvt_pk_f32_fp8(v.x, false); acc[0] += f.x;  acc[1] += f.y;
    f = __builtin_amdgcn_cvt_pk_f32_fp8(v.x, true);  acc[2] += f.x;  acc[3] += f.y;
    f = __builtin_amdgcn_cvt_pk_f32_fp8(v.y, false); acc[4] += f.x;  acc[5] += f.y;
    f = __builtin_amdgcn_cvt_pk_f32_fp8(v.y, true);  acc[6] += f.x;  acc[7] += f.y;
    f = __builtin_amdgcn_cvt_pk_f32_fp8(v.z, false); acc[8] += f.x;  acc[9] += f.y;
    f = __builtin_amdgcn_cvt_pk_f32_fp8(v.z, true);  acc[10] += f.x; acc[11] += f.y;
    f = __builtin_amdgcn_cvt_pk_f32_fp8(v.w, false); acc[12] += f.x; acc[13] += f.y;
    f = __builtin_amdgcn_cvt_pk_f32_fp8(v.w, true);  acc[14] += f.x; acc[15] += f.y;
}

__global__ void gather_kernel(const unsigned char* __restrict__ Xq,
                              const __half* __restrict__ Xh,
                              __half* __restrict__ Zh,
                              const int* __restrict__ row_ptr,
                              const int* __restrict__ csr_src) {
    int wave = (blockIdx.x * blockDim.x + threadIdx.x) >> 6;
    int lane = threadIdx.x & 63;
    if (wave >= N_NODES) return;
    const int grp = lane >> 3;     // 0..7
    const int m   = lane & 7;      // 0..7
    const uint4* Q = (const uint4*)Xq;   // row = 8 x uint4 (128B)

    float acc[16];
#pragma unroll
    for (int j = 0; j < 16; ++j) acc[j] = 0.f;

    int k = row_ptr[wave];
    const int end = row_ptr[wave + 1];

    for (; k + 16 <= end; k += 16) {
        int n0 = csr_src[k + grp];
        int n1 = csr_src[k + 8 + grp];
        uint4 v0 = Q[(size_t)n0 * 8 + m];
        uint4 v1 = Q[(size_t)n1 * 8 + m];
        acc_fp8x16(acc, v0);
        acc_fp8x16(acc, v1);
    }
    if (k + 8 <= end) {
        int n0 = csr_src[k + grp];
        uint4 v0 = Q[(size_t)n0 * 8 + m];
        acc_fp8x16(acc, v0);
        k += 8;
    }
    int rem = end - k;             // 0..7
    if (grp < rem) {
        int n0 = csr_src[k + grp];
        uint4 v0 = Q[(size_t)n0 * 8 + m];
        acc_fp8x16(acc, v0);
    }

    // pack partials to 8 x half2, butterfly with v_pk_add_f16 (xor 8/16/32)
    half2v hh[8];
#pragma unroll
    for (int j = 0; j < 8; ++j) {
        hh[j][0] = (_Float16)acc[2 * j];
        hh[j][1] = (_Float16)acc[2 * j + 1];
    }
#pragma unroll
    for (int j = 0; j < 8; ++j) {
        int b = __shfl_xor(__builtin_bit_cast(int, hh[j]), 8);
        hh[j] = hh[j] + __builtin_bit_cast(half2v, b);
    }
#pragma unroll
    for (int j = 0; j < 8; ++j) {
        int b = __shfl_xor(__builtin_bit_cast(int, hh[j]), 16);
        hh[j] = hh[j] + __builtin_bit_cast(half2v, b);
    }
#pragma unroll
    for (int j = 0; j < 8; ++j) {
        int b = __shfl_xor(__builtin_bit_cast(int, hh[j]), 32);
        hh[j] = hh[j] + __builtin_bit_cast(half2v, b);
    }

    // self term (fp16) + store, feats 16m..16m+15
    if (grp == 0) {
        const half2v* H2 = (const half2v*)(Xh + (size_t)wave * HIDDEN + 16 * m);
        half8 o0, o1;
#pragma unroll
        for (int j = 0; j < 4; ++j) {
            half2v s = hh[j] + H2[j];
            o0[2 * j] = s[0]; o0[2 * j + 1] = s[1];
        }
#pragma unroll
        for (int j = 0; j < 4; ++j) {
            half2v s = hh[4 + j] + H2[4 + j];
            o1[2 * j] = s[0]; o1[2 * j + 1] = s[1];
        }
        ((half8*)(Zh + (size_t)wave * HIDDEN + 16 * m))[0] = o0;
        ((half8*)(Zh + (size_t)wave * HIDDEN + 16 * m))[1] = o1;
    }
}

// ---------------------------------------------------------------------------
// Register-resident-W MFMA stage (R11-confirmed): C = relu(A@W + bias).
// ---------------------------------------------------------------------------
#define MM_BLOCKS 512
__global__ __launch_bounds__(256, 2) void mm_stage_kernel(const __half* __restrict__ A,
                                                          const __half* __restrict__ Wt,
                                                          const float* __restrict__ bias,
                                                          __half* __restrict__ C16) {
    const int gwave = (blockIdx.x * 256 + threadIdx.x) >> 6;
    const int lane  = threadIdx.x & 63;
    const int m = lane & 15;
    const int q = lane >> 4;
    const int nwaves = MM_BLOCKS * 4;
    const int NTILES = N_NODES / 16;   // 6250

    half8 wf[8][4];
    float bl[8];
#pragma unroll
    for (int ct = 0; ct < 8; ++ct) {
        const half8* Wrow = (const half8*)(Wt + (size_t)(ct * 16 + m) * HIDDEN);
#pragma unroll
        for (int c = 0; c < 4; ++c) wf[ct][c] = Wrow[c * 4 + q];
        bl[ct] = bias[ct * 16 + m];
    }

    for (int t = gwave; t < NTILES; t += nwaves) {
        const half8* Arow = (const half8*)(A + (size_t)(t * 16 + m) * HIDDEN);
        half8 a0 = Arow[q];
        half8 a1 = Arow[4 + q];
        half8 a2 = Arow[8 + q];
        half8 a3 = Arow[12 + q];
#pragma unroll
        for (int ct = 0; ct < 8; ++ct) {
            floatx4 acc = {0.f, 0.f, 0.f, 0.f};
            acc = __builtin_amdgcn_mfma_f32_16x16x32_f16(a0, wf[ct][0], acc, 0, 0, 0);
            acc = __builtin_amdgcn_mfma_f32_16x16x32_f16(a1, wf[ct][1], acc, 0, 0, 0);
            acc = __builtin_amdgcn_mfma_f32_16x16x32_f16(a2, wf[ct][2], acc, 0, 0, 0);
            acc = __builtin_amdgcn_mfma_f32_16x16x32_f16(a3, wf[ct][3], acc, 0, 0, 0);
            const int n = ct * 16 + m;
#pragma unroll
            for (int r = 0; r < 4; ++r) {
                int row = t * 16 + q * 4 + r;
                float v = fmaxf(acc[r] + bl[ct], 0.f);
                C16[(size_t)row * HIDDEN + n] = __float2half(v);
            }
        }
    }
}

// ---------------------------------------------------------------------------
// Pool (batch sorted) + optional fp8 twin emission (replaces h2q kernels).
// 64 threads, thread f2 owns feat pair {2f2, 2f2+1}; half2 loads; fp32 acc.
// ---------------------------------------------------------------------------
#define POOL_CHUNK 32
__global__ __launch_bounds__(64) void pool_kernel(const __half* __restrict__ Xh,
                                                  const int* __restrict__ batch,
                                                  float* __restrict__ pooled, int layer,
                                                  unsigned char* __restrict__ outq) {
    const int f2 = threadIdx.x;    // 0..63
    int start = blockIdx.x * POOL_CHUNK;
    int end = start + POOL_CHUNK;
    if (end > N_NODES) end = N_NODES;
    float ax = 0.f, ay = 0.f;
    int gcur = batch[start];
    for (int n = start; n < end; ++n) {
        int g = batch[n];
        if (g != gcur) {
            float* pd = &pooled[(size_t)gcur * (HIDDEN * N_LAYERS) + layer * HIDDEN + 2 * f2];
            atomicAdd(pd, ax);
            atomicAdd(pd + 1, ay);
            ax = 0.f; ay = 0.f;
            gcur = g;
        }
        __half2 v = ((const __half2*)(Xh + (size_t)n * HIDDEN))[f2];
        float2 fv = __half22float2(v);
        ax += fv.x; ay += fv.y;
        if (outq) {
            unsigned r = __builtin_amdgcn_cvt_pk_fp8_f32(fv.x, fv.y, 0, false);
            ((unsigned short*)(outq + (size_t)n * HIDDEN))[f2] = (unsigned short)(r & 0xffff);
        }
    }
    float* pd = &pooled[(size_t)gcur * (HIDDEN * N_LAYERS) + layer * HIDDEN + 2 * f2];
    atomicAdd(pd, ax);
    atomicAdd(pd + 1, ay);
}

// ---------------------------------------------------------------------------
__global__ __launch_bounds__(128) void cls_kernel(const float* __restrict__ pooled,
                                                  const float* __restrict__ w1,
                                                  const float* __restrict__ b1,
                                                  const float* __restrict__ w2,
                                                  const float* __restrict__ b2,
                                                  const float* __restrict__ w3,
                                                  const float* __restrict__ b3,
                                                  float* __restrict__ out) {
    __shared__ float hin[HIDDEN * N_LAYERS];
    __shared__ float h1[HIDDEN];
    __shared__ float red[HIDDEN];
    const int g = blockIdx.x;
    const int t = threadIdx.x;

    for (int i = t; i < HIDDEN * N_LAYERS; i += 128)
        hin[i] = pooled[(size_t)g * (HIDDEN * N_LAYERS) + i];
    __syncthreads();

    float s = 0.f;
    for (int k = 0; k < HIDDEN * N_LAYERS; ++k) s += hin[k] * w1[(size_t)k * HIDDEN + t];
    s = fmaxf(s + b1[t], 0.f);
    h1[t] = s;
    __syncthreads();

    float s2 = 0.f;
    for (int k = 0; k < HIDDEN; ++k) s2 += h1[k] * w2[(size_t)k * HIDDEN + t];
    s2 = fmaxf(s2 + b2[t], 0.f);

    red[t] = s2 * w3[t];
    __syncthreads();
    for (int off = 64; off > 0; off >>= 1) {
        if (t < off) red[t] += red[t + off];
        __syncthreads();
    }
    if (t == 0) out[g] = red[0] + b3[0];
}

// ---------------------------------------------------------------------------
extern "C" void kernel_launch(void* const* d_in, const int* in_sizes, int n_in,
                              void* d_out, int out_size, void* d_ws, size_t ws_size,
                              hipStream_t stream) {
    const float* X     = (const float*)d_in[0];
    const int*   ei    = (const int*)d_in[1];
    const int*   batch = (const int*)d_in[2];
    const float* w1all = (const float*)d_in[3];
    const float* b1all = (const float*)d_in[4];
    const float* w2all = (const float*)d_in[5];
    const float* b2all = (const float*)d_in[6];
    const float* cw1   = (const float*)d_in[7];
    const float* cb1   = (const float*)d_in[8];
    const float* cw2   = (const float*)d_in[9];
    const float* cb2   = (const float*)d_in[10];
    const float* cw3   = (const float*)d_in[11];
    const float* cb3   = (const float*)d_in[12];
    float* out = (float*)d_out;

    const int* src = ei;
    const int* dst = ei + N_EDGES;

    char* p = (char*)d_ws;
    auto alloc2 = [&](size_t bytes) {
        char* r = p;
        p += (bytes + 255) & ~(size_t)255;
        return r;
    };
    __half* hA      = (__half*)alloc2((size_t)N_NODES * HIDDEN * sizeof(__half));
    __half* hB      = (__half*)alloc2((size_t)N_NODES * HIDDEN * sizeof(__half));
    __half* zh      = (__half*)alloc2((size_t)N_NODES * HIDDEN * sizeof(__half));
    __half* m1h     = (__half*)alloc2((size_t)N_NODES * HIDDEN * sizeof(__half));
    unsigned char* qbuf = (unsigned char*)alloc2((size_t)N_NODES * HIDDEN);
    __half* wt1     = (__half*)alloc2((size_t)N_LAYERS * HIDDEN * HIDDEN * sizeof(__half));
    __half* wt2     = (__half*)alloc2((size_t)N_LAYERS * HIDDEN * HIDDEN * sizeof(__half));
    int2*   wedge   = (int2*)alloc2((size_t)N_EDGES * sizeof(int2));
    int*    csr     = (int*)alloc2((size_t)N_EDGES * sizeof(int));
    int*    rowp    = (int*)alloc2((size_t)(N_NODES + 1) * sizeof(int));
    int*    counts  = (int*)alloc2((size_t)PLACE_BLOCKS * N_WIN * sizeof(int));
    int*    offsets = (int*)alloc2((size_t)PLACE_BLOCKS * N_WIN * sizeof(int));
    int*    colsum  = (int*)alloc2((size_t)N_WIN * sizeof(int));
    int*    winbase = (int*)alloc2((size_t)(N_WIN + 1) * sizeof(int));
    float*  pooled  = (float*)alloc2((size_t)N_GRAPHS * HIDDEN * N_LAYERS * sizeof(float));

    hipMemsetAsync(pooled, 0, (size_t)N_GRAPHS * HIDDEN * N_LAYERS * sizeof(float), stream);

    win_count_kernel<<<PLACE_BLOCKS, 256, 0, stream>>>(dst, counts);
    win_scan1_kernel<<<N_WIN, 128, 0, stream>>>(counts, offsets, colsum);
    win_scan2_kernel<<<1, 512, 0, stream>>>(colsum, winbase);
    win_place_kernel<<<PLACE_BLOCKS, 256, 0, stream>>>(src, dst, offsets, winbase, wedge);
    win_csr_kernel<<<N_WIN, 256, 0, stream>>>(wedge, winbase, rowp, csr);

    const int cvt_grid = ((N_NODES * HIDDEN / 8) + 255) / 256;
    f2h_kernel<<<cvt_grid, 256, 0, stream>>>(X, hA, qbuf);
    wconv_kernel<<<N_LAYERS * 2 * 16, 256, 0, stream>>>(w1all, w2all, wt1, wt2);

    const int gat_grid  = (N_NODES + 3) / 4;
    const int pool_grid = (N_NODES + POOL_CHUNK - 1) / POOL_CHUNK;

    __half* hcur = hA;
    for (int l = 0; l < N_LAYERS; ++l) {
        __half* hnext = (l & 1) ? hA : hB;
        gather_kernel<<<gat_grid, 256, 0, stream>>>(qbuf, hcur, zh, rowp, csr);
        mm_stage_kernel<<<MM_BLOCKS, 256, 0, stream>>>(zh,
                                                       wt1 + (size_t)l * HIDDEN * HIDDEN,
                                                       b1all + (size_t)l * HIDDEN,
                                                       m1h);
        mm_stage_kernel<<<MM_BLOCKS, 256, 0, stream>>>(m1h,
                                                       wt2 + (size_t)l * HIDDEN * HIDDEN,
                                                       b2all + (size_t)l * HIDDEN,
                                                       hnext);
        pool_kernel<<<pool_grid, 64, 0, stream>>>(hnext, batch, pooled, l,
                                                  (l < N_LAYERS - 1) ? qbuf : nullptr);
        hcur = hnext;
    }

    cls_kernel<<<N_GRAPHS, 128, 0, stream>>>(pooled, cw1, cb1, cw2, cb2, cw3, cb3, out);
}

// Round 14
// 478.474 us; speedup vs baseline: 1.2444x; 1.0188x over previous
//
#include <hip/hip_runtime.h>
#include <hip/hip_fp16.h>
#include <cstddef>
#include <cstdint>

#define N_NODES   100000
#define N_EDGES   1600000
#define N_GRAPHS  512
#define HIDDEN    128
#define N_LAYERS  3

// 400-way counting sort (R9-confirmed). 128 place blocks (R13: ~31-edge runs
// per window -> near-full-line wedge writes).
#define N_WIN        400
#define WIN_NODES    (N_NODES / N_WIN)      // 250
#define PLACE_BLOCKS 128
#define PCHUNK       (N_EDGES / PLACE_BLOCKS)  // 12500, divisible by 4

#define F2H_BLOCKS   ((N_NODES * HIDDEN / 8) / 256)            // 6250
#define WCONV_BLOCKS (N_LAYERS * 2 * 16)                       // 96
#define PZERO_BLOCKS ((N_GRAPHS * HIDDEN * N_LAYERS) / 256)    // 768
#define PREP_BLOCKS  (F2H_BLOCKS + WCONV_BLOCKS + PZERO_BLOCKS)

typedef _Float16 half8  __attribute__((ext_vector_type(8)));
typedef _Float16 half4v __attribute__((ext_vector_type(4)));
typedef _Float16 half2v __attribute__((ext_vector_type(2)));
typedef float    float8 __attribute__((ext_vector_type(8)));
typedef float    floatx4 __attribute__((ext_vector_type(4)));
typedef float    floatx2 __attribute__((ext_vector_type(2)));

// ---------------------------------------------------------------------------
__global__ __launch_bounds__(256) void win_count_kernel(const int* __restrict__ dst,
                                                        int* __restrict__ counts) {
    __shared__ int cs[N_WIN];
    for (int i = threadIdx.x; i < N_WIN; i += 256) cs[i] = 0;
    __syncthreads();
    const int4* d4 = (const int4*)(dst + blockIdx.x * PCHUNK);
    for (int i = threadIdx.x; i < PCHUNK / 4; i += 256) {
        int4 d = d4[i];
        atomicAdd(&cs[d.x / WIN_NODES], 1);
        atomicAdd(&cs[d.y / WIN_NODES], 1);
        atomicAdd(&cs[d.z / WIN_NODES], 1);
        atomicAdd(&cs[d.w / WIN_NODES], 1);
    }
    __syncthreads();
    for (int i = threadIdx.x; i < N_WIN; i += 256)
        counts[blockIdx.x * N_WIN + i] = cs[i];
}

// column scan over the 128 place-blocks; emits per-block offsets + col totals
__global__ __launch_bounds__(128) void win_scan1_kernel(const int* __restrict__ counts,
                                                        int* __restrict__ offsets,
                                                        int* __restrict__ colsum) {
    __shared__ int tmp[128];
    const int w = blockIdx.x;
    const int t = threadIdx.x;
    tmp[t] = counts[t * N_WIN + w];
    __syncthreads();
#pragma unroll
    for (int off = 1; off < 128; off <<= 1) {
        int u = (t >= off) ? tmp[t - off] : 0;
        __syncthreads();
        tmp[t] += u;
        __syncthreads();
    }
    offsets[t * N_WIN + w] = (t == 0) ? 0 : tmp[t - 1];
    if (t == 127) colsum[w] = tmp[127];
}

// place: re-derives winbase from colsum via in-LDS scan (win_scan2 removed)
__global__ __launch_bounds__(512) void win_place_kernel(const int* __restrict__ src,
                                                        const int* __restrict__ dst,
                                                        const int* __restrict__ offsets,
                                                        const int* __restrict__ colsum,
                                                        int2* __restrict__ wedge) {
    __shared__ int ws[512];
    __shared__ int off[N_WIN];
    const int t = threadIdx.x;
    ws[t] = (t < N_WIN) ? colsum[t] : 0;
    __syncthreads();
#pragma unroll
    for (int o = 1; o < 512; o <<= 1) {
        int u = (t >= o) ? ws[t - o] : 0;
        __syncthreads();
        ws[t] += u;
        __syncthreads();
    }
    if (t < N_WIN) off[t] = offsets[blockIdx.x * N_WIN + t] + ((t == 0) ? 0 : ws[t - 1]);
    __syncthreads();
    const int4* d4 = (const int4*)(dst + blockIdx.x * PCHUNK);
    const int4* s4 = (const int4*)(src + blockIdx.x * PCHUNK);
    for (int i = t; i < PCHUNK / 4; i += 512) {
        int4 d = d4[i];
        int4 s = s4[i];
        int p0 = atomicAdd(&off[d.x / WIN_NODES], 1); wedge[p0] = make_int2(d.x, s.x);
        int p1 = atomicAdd(&off[d.y / WIN_NODES], 1); wedge[p1] = make_int2(d.y, s.y);
        int p2 = atomicAdd(&off[d.z / WIN_NODES], 1); wedge[p2] = make_int2(d.z, s.z);
        int p3 = atomicAdd(&off[d.w / WIN_NODES], 1); wedge[p3] = make_int2(d.w, s.w);
    }
}

// fused per-window CSR: winbase scan -> count -> scan -> row_ptr -> scatter
__global__ __launch_bounds__(512) void win_csr_kernel(const int2* __restrict__ wedge,
                                                      const int* __restrict__ colsum,
                                                      int* __restrict__ row_ptr,
                                                      int* __restrict__ csr_src) {
    __shared__ int ws[512];
    __shared__ int cnt[WIN_NODES];
    __shared__ int bb[2];
    const int w = blockIdx.x, n0 = w * WIN_NODES, t = threadIdx.x;
    ws[t] = (t < N_WIN) ? colsum[t] : 0;
    __syncthreads();
#pragma unroll
    for (int o = 1; o < 512; o <<= 1) {
        int u = (t >= o) ? ws[t - o] : 0;
        __syncthreads();
        ws[t] += u;
        __syncthreads();
    }
    if (t == 0) { bb[0] = (w > 0) ? ws[w - 1] : 0; bb[1] = ws[w]; }
    if (w == N_WIN - 1 && t == 0) row_ptr[N_NODES] = ws[N_WIN - 1];
    for (int i = t; i < WIN_NODES; i += 512) cnt[i] = 0;
    __syncthreads();
    const int b0 = bb[0], b1 = bb[1];
    for (int e = b0 + t; e < b1; e += 512)
        atomicAdd(&cnt[wedge[e].x - n0], 1);
    __syncthreads();
    ws[t] = (t < WIN_NODES) ? cnt[t] : 0;
    __syncthreads();
#pragma unroll
    for (int o = 1; o < 512; o <<= 1) {
        int u = (t >= o) ? ws[t - o] : 0;
        __syncthreads();
        ws[t] += u;
        __syncthreads();
    }
    const int excl = (t == 0) ? 0 : ws[t - 1];
    if (t < WIN_NODES) {
        row_ptr[n0 + t] = b0 + excl;
        cnt[t] = b0 + excl;
    }
    __syncthreads();
    for (int e = b0 + t; e < b1; e += 512) {
        int2 ed = wedge[e];
        int p = atomicAdd(&cnt[ed.x - n0], 1);
        csr_src[p] = ed.y;
    }
}

// ---------------------------------------------------------------------------
// prep: grid-split fusion of (a) X fp32->fp16+fp8, (b) LDS-tiled weight
// transpose, (c) pooled zero-init. 3 launches -> 1 (R13: launch/gap overhead
// is a first-class cost at 22 dispatches).
// ---------------------------------------------------------------------------
__global__ __launch_bounds__(256) void prep_kernel(const float* __restrict__ X,
                                                   __half* __restrict__ hA,
                                                   unsigned char* __restrict__ outq,
                                                   const float* __restrict__ w1,
                                                   const float* __restrict__ w2,
                                                   __half* __restrict__ wt1,
                                                   __half* __restrict__ wt2,
                                                   float* __restrict__ pooled) {
    __shared__ float tile[32][33];
    const int b = blockIdx.x;
    if (b < F2H_BLOCKS) {
        int t = b * 256 + threadIdx.x;
        const float4* in4 = (const float4*)X;
        float4 a = in4[t * 2 + 0];
        float4 c = in4[t * 2 + 1];
        __half2* o2 = (__half2*)hA;
        o2[t * 4 + 0] = __floats2half2_rn(a.x, a.y);
        o2[t * 4 + 1] = __floats2half2_rn(a.z, a.w);
        o2[t * 4 + 2] = __floats2half2_rn(c.x, c.y);
        o2[t * 4 + 3] = __floats2half2_rn(c.z, c.w);
        unsigned r0 = 0, r1 = 0;
        r0 = __builtin_amdgcn_cvt_pk_fp8_f32(a.x, a.y, r0, false);
        r0 = __builtin_amdgcn_cvt_pk_fp8_f32(a.z, a.w, r0, true);
        r1 = __builtin_amdgcn_cvt_pk_fp8_f32(c.x, c.y, r1, false);
        r1 = __builtin_amdgcn_cvt_pk_fp8_f32(c.z, c.w, r1, true);
        ((uint2*)outq)[t] = make_uint2(r0, r1);
    } else if (b < F2H_BLOCKS + WCONV_BLOCKS) {
        const int bb = b - F2H_BLOCKS;
        const int mat = bb & 1;
        const int tt = (bb >> 1) & 15;
        const int l  = bb >> 5;
        const int ti = (tt >> 2) * 32, tj = (tt & 3) * 32;
        const float* W = (mat ? w2 : w1) + (size_t)l * HIDDEN * HIDDEN;
        __half* WT = (mat ? wt2 : wt1) + (size_t)l * HIDDEN * HIDDEN;
        const int r = threadIdx.x >> 5;
        const int c = threadIdx.x & 31;
#pragma unroll
        for (int rr = 0; rr < 4; ++rr)
            tile[r + 8 * rr][c] = W[(size_t)(ti + r + 8 * rr) * HIDDEN + tj + c];
        __syncthreads();
#pragma unroll
        for (int rr = 0; rr < 4; ++rr)
            WT[(size_t)(tj + r + 8 * rr) * HIDDEN + ti + c] =
                __float2half(tile[c][r + 8 * rr]);
    } else {
        int idx = (b - F2H_BLOCKS - WCONV_BLOCKS) * 256 + threadIdx.x;
        pooled[idx] = 0.f;
    }
}

// ---------------------------------------------------------------------------
// GIN aggregation, fp8 neighbors, packed-fp16 butterfly (R12/R13-confirmed).
// ---------------------------------------------------------------------------
__device__ __forceinline__ void acc_fp8x16(float* acc, uint4 v) {
    floatx2 f;
    f = __builtin_amdgcn_cvt_pk_f32_fp8(v.x, false); acc[0] += f.x;  acc[1] += f.y;
    f = __builtin_amdgcn_cvt_pk_f32_fp8(v.x, true);  acc[2] += f.x;  acc[3] += f.y;
    f = __builtin_amdgcn_cvt_pk_f32_fp8(v.y, false); acc[4] += f.x;  acc[5] += f.y;
    f = __builtin_amdgcn_cvt_pk_f32_fp8(v.y, true);  acc[6] += f.x;  acc[7] += f.y;
    f = __builtin_amdgcn_cvt_pk_f32_fp8(v.z, false); acc[8] += f.x;  acc[9] += f.y;
    f = __builtin_amdgcn_cvt_pk_f32_fp8(v.z, true);  acc[10] += f.x; acc[11] += f.y;
    f = __builtin_amdgcn_cvt_pk_f32_fp8(v.w, false); acc[12] += f.x; acc[13] += f.y;
    f = __builtin_amdgcn_cvt_pk_f32_fp8(v.w, true);  acc[14] += f.x; acc[15] += f.y;
}

__global__ void gather_kernel(const unsigned char* __restrict__ Xq,
                              const __half* __restrict__ Xh,
                              __half* __restrict__ Zh,
                              const int* __restrict__ row_ptr,
                              const int* __restrict__ csr_src) {
    int wave = (blockIdx.x * blockDim.x + threadIdx.x) >> 6;
    int lane = threadIdx.x & 63;
    if (wave >= N_NODES) return;
    const int grp = lane >> 3;     // 0..7
    const int m   = lane & 7;      // 0..7
    const uint4* Q = (const uint4*)Xq;   // row = 8 x uint4 (128B)

    float acc[16];
#pragma unroll
    for (int j = 0; j < 16; ++j) acc[j] = 0.f;

    int k = row_ptr[wave];
    const int end = row_ptr[wave + 1];

    for (; k + 16 <= end; k += 16) {
        int n0 = csr_src[k + grp];
        int n1 = csr_src[k + 8 + grp];
        uint4 v0 = Q[(size_t)n0 * 8 + m];
        uint4 v1 = Q[(size_t)n1 * 8 + m];
        acc_fp8x16(acc, v0);
        acc_fp8x16(acc, v1);
    }
    if (k + 8 <= end) {
        int n0 = csr_src[k + grp];
        uint4 v0 = Q[(size_t)n0 * 8 + m];
        acc_fp8x16(acc, v0);
        k += 8;
    }
    int rem = end - k;
    if (grp < rem) {
        int n0 = csr_src[k + grp];
        uint4 v0 = Q[(size_t)n0 * 8 + m];
        acc_fp8x16(acc, v0);
    }

    half2v hh[8];
#pragma unroll
    for (int j = 0; j < 8; ++j) {
        hh[j][0] = (_Float16)acc[2 * j];
        hh[j][1] = (_Float16)acc[2 * j + 1];
    }
#pragma unroll
    for (int j = 0; j < 8; ++j) {
        int b = __shfl_xor(__builtin_bit_cast(int, hh[j]), 8);
        hh[j] = hh[j] + __builtin_bit_cast(half2v, b);
    }
#pragma unroll
    for (int j = 0; j < 8; ++j) {
        int b = __shfl_xor(__builtin_bit_cast(int, hh[j]), 16);
        hh[j] = hh[j] + __builtin_bit_cast(half2v, b);
    }
#pragma unroll
    for (int j = 0; j < 8; ++j) {
        int b = __shfl_xor(__builtin_bit_cast(int, hh[j]), 32);
        hh[j] = hh[j] + __builtin_bit_cast(half2v, b);
    }

    if (grp == 0) {
        const half2v* H2 = (const half2v*)(Xh + (size_t)wave * HIDDEN + 16 * m);
        half8 o0, o1;
#pragma unroll
        for (int j = 0; j < 4; ++j) {
            half2v s = hh[j] + H2[j];
            o0[2 * j] = s[0]; o0[2 * j + 1] = s[1];
        }
#pragma unroll
        for (int j = 0; j < 4; ++j) {
            half2v s = hh[4 + j] + H2[4 + j];
            o1[2 * j] = s[0]; o1[2 * j + 1] = s[1];
        }
        ((half8*)(Zh + (size_t)wave * HIDDEN + 16 * m))[0] = o0;
        ((half8*)(Zh + (size_t)wave * HIDDEN + 16 * m))[1] = o1;
    }
}

// ---------------------------------------------------------------------------
// Register-resident-W MFMA stage, SWAPPED operands (R13: epilogue was 2B
// scalar stores). mfma(wf, a) computes the transposed tile: lane = node,
// regs = 4 consecutive output cols -> half4 (8B) vector stores, 8/tile vs 32.
// Loads unchanged (A/B fragment layouts are symmetric). Bias indexed by
// n = ct*16 + q*4 + r.
// ---------------------------------------------------------------------------
#define MM_BLOCKS 512
__global__ __launch_bounds__(256, 2) void mm_stage_kernel(const __half* __restrict__ A,
                                                          const __half* __restrict__ Wt,
                                                          const float* __restrict__ bias,
                                                          __half* __restrict__ C16) {
    const int gwave = (blockIdx.x * 256 + threadIdx.x) >> 6;
    const int lane  = threadIdx.x & 63;
    const int m = lane & 15;
    const int q = lane >> 4;
    const int nwaves = MM_BLOCKS * 4;
    const int NTILES = N_NODES / 16;   // 6250

    half8 wf[8][4];
    float bl[8][4];
#pragma unroll
    for (int ct = 0; ct < 8; ++ct) {
        const half8* Wrow = (const half8*)(Wt + (size_t)(ct * 16 + m) * HIDDEN);
#pragma unroll
        for (int c = 0; c < 4; ++c) wf[ct][c] = Wrow[c * 4 + q];
#pragma unroll
        for (int r = 0; r < 4; ++r) bl[ct][r] = bias[ct * 16 + q * 4 + r];
    }

    for (int t = gwave; t < NTILES; t += nwaves) {
        const half8* Arow = (const half8*)(A + (size_t)(t * 16 + m) * HIDDEN);
        half8 a0 = Arow[q];
        half8 a1 = Arow[4 + q];
        half8 a2 = Arow[8 + q];
        half8 a3 = Arow[12 + q];
        __half* Cr = C16 + (size_t)(t * 16 + m) * HIDDEN + q * 4;
#pragma unroll
        for (int ct = 0; ct < 8; ++ct) {
            floatx4 acc = {0.f, 0.f, 0.f, 0.f};
            acc = __builtin_amdgcn_mfma_f32_16x16x32_f16(wf[ct][0], a0, acc, 0, 0, 0);
            acc = __builtin_amdgcn_mfma_f32_16x16x32_f16(wf[ct][1], a1, acc, 0, 0, 0);
            acc = __builtin_amdgcn_mfma_f32_16x16x32_f16(wf[ct][2], a2, acc, 0, 0, 0);
            acc = __builtin_amdgcn_mfma_f32_16x16x32_f16(wf[ct][3], a3, acc, 0, 0, 0);
            half4v o;
#pragma unroll
            for (int r = 0; r < 4; ++r)
                o[r] = (_Float16)fmaxf(acc[r] + bl[ct][r], 0.f);
            *(half4v*)(Cr + ct * 16) = o;
        }
    }
}

// ---------------------------------------------------------------------------
// Pool (batch sorted) + optional fp8 twin emission (R13-confirmed).
// ---------------------------------------------------------------------------
#define POOL_CHUNK 32
__global__ __launch_bounds__(64) void pool_kernel(const __half* __restrict__ Xh,
                                                  const int* __restrict__ batch,
                                                  float* __restrict__ pooled, int layer,
                                                  unsigned char* __restrict__ outq) {
    const int f2 = threadIdx.x;    // 0..63
    int start = blockIdx.x * POOL_CHUNK;
    int end = start + POOL_CHUNK;
    if (end > N_NODES) end = N_NODES;
    float ax = 0.f, ay = 0.f;
    int gcur = batch[start];
    for (int n = start; n < end; ++n) {
        int g = batch[n];
        if (g != gcur) {
            float* pd = &pooled[(size_t)gcur * (HIDDEN * N_LAYERS) + layer * HIDDEN + 2 * f2];
            atomicAdd(pd, ax);
            atomicAdd(pd + 1, ay);
            ax = 0.f; ay = 0.f;
            gcur = g;
        }
        __half2 v = ((const __half2*)(Xh + (size_t)n * HIDDEN))[f2];
        float2 fv = __half22float2(v);
        ax += fv.x; ay += fv.y;
        if (outq) {
            unsigned r = __builtin_amdgcn_cvt_pk_fp8_f32(fv.x, fv.y, 0, false);
            ((unsigned short*)(outq + (size_t)n * HIDDEN))[f2] = (unsigned short)(r & 0xffff);
        }
    }
    float* pd = &pooled[(size_t)gcur * (HIDDEN * N_LAYERS) + layer * HIDDEN + 2 * f2];
    atomicAdd(pd, ax);
    atomicAdd(pd + 1, ay);
}

// ---------------------------------------------------------------------------
__global__ __launch_bounds__(128) void cls_kernel(const float* __restrict__ pooled,
                                                  const float* __restrict__ w1,
                                                  const float* __restrict__ b1,
                                                  const float* __restrict__ w2,
                                                  const float* __restrict__ b2,
                                                  const float* __restrict__ w3,
                                                  const float* __restrict__ b3,
                                                  float* __restrict__ out) {
    __shared__ float hin[HIDDEN * N_LAYERS];
    __shared__ float h1[HIDDEN];
    __shared__ float red[HIDDEN];
    const int g = blockIdx.x;
    const int t = threadIdx.x;

    for (int i = t; i < HIDDEN * N_LAYERS; i += 128)
        hin[i] = pooled[(size_t)g * (HIDDEN * N_LAYERS) + i];
    __syncthreads();

    float s = 0.f;
    for (int k = 0; k < HIDDEN * N_LAYERS; ++k) s += hin[k] * w1[(size_t)k * HIDDEN + t];
    s = fmaxf(s + b1[t], 0.f);
    h1[t] = s;
    __syncthreads();

    float s2 = 0.f;
    for (int k = 0; k < HIDDEN; ++k) s2 += h1[k] * w2[(size_t)k * HIDDEN + t];
    s2 = fmaxf(s2 + b2[t], 0.f);

    red[t] = s2 * w3[t];
    __syncthreads();
    for (int off = 64; off > 0; off >>= 1) {
        if (t < off) red[t] += red[t + off];
        __syncthreads();
    }
    if (t == 0) out[g] = red[0] + b3[0];
}

// ---------------------------------------------------------------------------
extern "C" void kernel_launch(void* const* d_in, const int* in_sizes, int n_in,
                              void* d_out, int out_size, void* d_ws, size_t ws_size,
                              hipStream_t stream) {
    const float* X     = (const float*)d_in[0];
    const int*   ei    = (const int*)d_in[1];
    const int*   batch = (const int*)d_in[2];
    const float* w1all = (const float*)d_in[3];
    const float* b1all = (const float*)d_in[4];
    const float* w2all = (const float*)d_in[5];
    const float* b2all = (const float*)d_in[6];
    const float* cw1   = (const float*)d_in[7];
    const float* cb1   = (const float*)d_in[8];
    const float* cw2   = (const float*)d_in[9];
    const float* cb2   = (const float*)d_in[10];
    const float* cw3   = (const float*)d_in[11];
    const float* cb3   = (const float*)d_in[12];
    float* out = (float*)d_out;

    const int* src = ei;
    const int* dst = ei + N_EDGES;

    char* p = (char*)d_ws;
    auto alloc2 = [&](size_t bytes) {
        char* r = p;
        p += (bytes + 255) & ~(size_t)255;
        return r;
    };
    __half* hA      = (__half*)alloc2((size_t)N_NODES * HIDDEN * sizeof(__half));
    __half* hB      = (__half*)alloc2((size_t)N_NODES * HIDDEN * sizeof(__half));
    __half* zh      = (__half*)alloc2((size_t)N_NODES * HIDDEN * sizeof(__half));
    __half* m1h     = (__half*)alloc2((size_t)N_NODES * HIDDEN * sizeof(__half));
    unsigned char* qbuf = (unsigned char*)alloc2((size_t)N_NODES * HIDDEN);
    __half* wt1     = (__half*)alloc2((size_t)N_LAYERS * HIDDEN * HIDDEN * sizeof(__half));
    __half* wt2     = (__half*)alloc2((size_t)N_LAYERS * HIDDEN * HIDDEN * sizeof(__half));
    int2*   wedge   = (int2*)alloc2((size_t)N_EDGES * sizeof(int2));
    int*    csr     = (int*)alloc2((size_t)N_EDGES * sizeof(int));
    int*    rowp    = (int*)alloc2((size_t)(N_NODES + 1) * sizeof(int));
    int*    counts  = (int*)alloc2((size_t)PLACE_BLOCKS * N_WIN * sizeof(int));
    int*    offsets = (int*)alloc2((size_t)PLACE_BLOCKS * N_WIN * sizeof(int));
    int*    colsum  = (int*)alloc2((size_t)N_WIN * sizeof(int));
    float*  pooled  = (float*)alloc2((size_t)N_GRAPHS * HIDDEN * N_LAYERS * sizeof(float));

    // CSR build: count -> column scan -> place -> fused per-window csr
    win_count_kernel<<<PLACE_BLOCKS, 256, 0, stream>>>(dst, counts);
    win_scan1_kernel<<<N_WIN, 128, 0, stream>>>(counts, offsets, colsum);
    win_place_kernel<<<PLACE_BLOCKS, 512, 0, stream>>>(src, dst, offsets, colsum, wedge);
    win_csr_kernel<<<N_WIN, 512, 0, stream>>>(wedge, colsum, rowp, csr);

    // fused prep: X conversions + weight transpose + pooled zero
    prep_kernel<<<PREP_BLOCKS, 256, 0, stream>>>(X, hA, qbuf, w1all, w2all, wt1, wt2, pooled);

    const int gat_grid  = (N_NODES + 3) / 4;
    const int pool_grid = (N_NODES + POOL_CHUNK - 1) / POOL_CHUNK;

    __half* hcur = hA;
    for (int l = 0; l < N_LAYERS; ++l) {
        __half* hnext = (l & 1) ? hA : hB;
        gather_kernel<<<gat_grid, 256, 0, stream>>>(qbuf, hcur, zh, rowp, csr);
        mm_stage_kernel<<<MM_BLOCKS, 256, 0, stream>>>(zh,
                                                       wt1 + (size_t)l * HIDDEN * HIDDEN,
                                                       b1all + (size_t)l * HIDDEN,
                                                       m1h);
        mm_stage_kernel<<<MM_BLOCKS, 256, 0, stream>>>(m1h,
                                                       wt2 + (size_t)l * HIDDEN * HIDDEN,
                                                       b2all + (size_t)l * HIDDEN,
                                                       hnext);
        pool_kernel<<<pool_grid, 64, 0, stream>>>(hnext, batch, pooled, l,
                                                  (l < N_LAYERS - 1) ? qbuf : nullptr);
        hcur = hnext;
    }

    cls_kernel<<<N_GRAPHS, 128, 0, stream>>>(pooled, cw1, cb1, cw2, cb2, cw3, cb3, out);
}